// Round 5
// baseline (346.408 us; speedup 1.0000x reference)
//
#include <hip/hip_runtime.h>
#include <hip/hip_bf16.h>
#include <math.h>

// ---------------- constants ----------------
#define SEQ   4096
#define BATCH 2
#define DM    768
#define DI    1152
#define NHEAD 12
#define DH    64
#define NTOK  (BATCH * SEQ)   // 8192
#define HALFW 64              // WINDOW//2

typedef unsigned short u16;
typedef __attribute__((ext_vector_type(8))) short   short8;   // 8 bf16 = MFMA A/B frag
typedef __attribute__((ext_vector_type(4))) float   f32x4;    // MFMA C/D frag
typedef __attribute__((ext_vector_type(8))) unsigned short ushort8;

__device__ __forceinline__ u16 f2bf(float f) {
    unsigned int u = __float_as_uint(f);
    u += 0x7fffu + ((u >> 16) & 1u);   // RNE
    return (u16)(u >> 16);
}
__device__ __forceinline__ float bf2f(u16 b) {
    return __uint_as_float(((unsigned int)b) << 16);
}

__device__ __forceinline__ void gload16(const void* g, void* l) {
    __builtin_amdgcn_global_load_lds(
        (const __attribute__((address_space(1))) void*)g,
        (__attribute__((address_space(3))) void*)l, 16, 0, 0);
}

__device__ __forceinline__ float gelu_tanh(float v) {
    return 0.5f * v * (1.0f + tanhf(0.7978845608028654f * (v + 0.044715f * v * v * v)));
}

// ---------------- weight transpose + bf16 convert ----------------
__global__ __launch_bounds__(256)
void wtrans_kernel(const float* __restrict__ W, u16* __restrict__ WT, int K, int N) {
    __shared__ float S[32][33];
    const int tn = blockIdx.x, tk = blockIdx.y;
    const int tx = threadIdx.x & 31, ty = threadIdx.x >> 5;
    #pragma unroll
    for (int i = 0; i < 4; ++i) {
        const int r = ty + i * 8;
        S[r][tx] = W[(size_t)(tk * 32 + r) * N + tn * 32 + tx];
    }
    __syncthreads();
    #pragma unroll
    for (int i = 0; i < 4; ++i) {
        const int r = ty + i * 8;
        WT[(size_t)(tn * 32 + r) * K + tk * 32 + tx] = f2bf(S[tx][r]);
    }
}

// ---------------- rope cos/sin table: [s][j], j=0..31 ----------------
__global__ __launch_bounds__(256)
void rope_table_kernel(float* __restrict__ cosT, float* __restrict__ sinT) {
    const int id = blockIdx.x * 256 + threadIdx.x;   // SEQ*32
    const int j = id & 31, s = id >> 5;
    const float inv = powf(10000.0f, -(float)j * (1.0f / 32.0f));
    const float ph = (float)s * inv;
    cosT[id] = cosf(ph);
    sinT[id] = sinf(ph);
}

// ---------------- RMSNorm (fp32 in -> bf16 out) ----------------
__global__ __launch_bounds__(256)
void rmsnorm_kernel(const float* __restrict__ x, const float* __restrict__ g,
                    u16* __restrict__ out) {
    const int row = blockIdx.x;
    const int t = threadIdx.x;
    const float* xr = x + (size_t)row * DM;
    float a = xr[t], b = xr[t + 256], c = xr[t + 512];
    float ss = a * a + b * b + c * c;
    #pragma unroll
    for (int o = 32; o > 0; o >>= 1) ss += __shfl_xor(ss, o);
    __shared__ float red[4];
    if ((t & 63) == 0) red[t >> 6] = ss;
    __syncthreads();
    float tot = red[0] + red[1] + red[2] + red[3];
    float inv = 1.0f / sqrtf(tot * (1.0f / DM) + 1e-5f);
    u16* orow = out + (size_t)row * DM;
    orow[t]       = f2bf(a * inv * g[t]);
    orow[t + 256] = f2bf(b * inv * g[t + 256]);
    orow[t + 512] = f2bf(c * inv * g[t + 512]);
}

// ---------------- bf16 MFMA GEMM (triple-buffered, counted vmcnt, XCD-swizzled) --
// A bf16 [M][K]; B (and B2) bf16 [N][K] pre-transposed.
// EPI: 0 none, 3 swiglu (gelu(acc1)*acc2, needs DUAL).  RES: += R(fp32).
// OBF: bf16 out else fp32.  1D grid, nbn = N/128 passed in.
// Pipeline: 2-deep prefetch; vmcnt(L) with in-order retirement == "tile t landed"
// while tile t+1's loads stay in flight across the raw s_barrier (T3/T4 minimum).
template<int EPI, bool RES, bool OBF, bool DUAL>
__global__ __launch_bounds__(256)
void bgemm_kernel(const u16* __restrict__ A, const u16* __restrict__ B,
                  const u16* __restrict__ B2, void* __restrict__ Cv,
                  const float* __restrict__ R, int M, int N, int K, int nbn) {
    __shared__ u16 As[3 * 4096];
    __shared__ u16 Bs[3 * 4096];
    __shared__ u16 B2s[DUAL ? 3 * 4096 : 2];
    const int t = threadIdx.x;
    const int w = t >> 6, l = t & 63;
    const int wm = w >> 1, wn = w & 1;

    // bijective XCD swizzle (m204): each XCD gets a contiguous wgid chunk;
    // bn fastest within chunk -> consecutive same-XCD blocks share the A-tile.
    const int nb = gridDim.x;
    const int orig = blockIdx.x;
    const int qq = nb >> 3, rr = nb & 7;
    const int xcd = orig & 7, cidx = orig >> 3;
    const int wgid = (xcd < rr ? xcd * (qq + 1) : rr * (qq + 1) + (xcd - rr) * qq) + cidx;
    const int bm = wgid / nbn, bn = wgid % nbn;

    // staging: slot s holds row m=s>>2, k-chunk ((s&3) ^ ((s>>3)&3))
    const int s0 = (w * 2 + 0) * 64 + l;
    const int s1 = (w * 2 + 1) * 64 + l;
    const int am0 = s0 >> 2, ak0 = ((s0 & 3) ^ ((s0 >> 3) & 3)) * 8;
    const int am1 = s1 >> 2, ak1 = ((s1 & 3) ^ ((s1 >> 3) & 3)) * 8;
    const u16* aSrc0 = A + (size_t)(bm * 128 + am0) * K + ak0;
    const u16* aSrc1 = A + (size_t)(bm * 128 + am1) * K + ak1;
    const u16* bSrc0 = B + (size_t)(bn * 128 + am0) * K + ak0;
    const u16* bSrc1 = B + (size_t)(bn * 128 + am1) * K + ak1;
    const u16* cSrc0 = DUAL ? B2 + (size_t)(bn * 128 + am0) * K + ak0 : nullptr;
    const u16* cSrc1 = DUAL ? B2 + (size_t)(bn * 128 + am1) * K + ak1 : nullptr;
    const int dS0 = (w * 2 + 0) * 512;   // u16 offset of this thread's wave-row base
    const int dS1 = (w * 2 + 1) * 512;

    const int lm = l & 15, lk = l >> 4;
    const int xoff = ((lk ^ ((lm >> 1) & 3)) * 16);   // byte offset within 64B row

    f32x4 acc[4][4] = {};
    f32x4 acc2[4][4] = {};

    const int nk = K >> 5;   // >= 24 for all our shapes

#define STAGE(off)  do {                                                       \
        u16* a_ = As + (off);  u16* b_ = Bs + (off);                           \
        gload16(aSrc0, a_ + dS0);  gload16(aSrc1, a_ + dS1);                   \
        gload16(bSrc0, b_ + dS0);  gload16(bSrc1, b_ + dS1);                   \
        if (DUAL) { u16* c_ = B2s + (off);                                     \
                    gload16(cSrc0, c_ + dS0);  gload16(cSrc1, c_ + dS1); }     \
        aSrc0 += 32; aSrc1 += 32; bSrc0 += 32; bSrc1 += 32;                    \
        if (DUAL) { cSrc0 += 32; cSrc1 += 32; }                                \
    } while (0)

    STAGE(0);        // tile 0 -> buf0
    STAGE(4096);     // tile 1 -> buf1
    int oC = 0, oN = 4096, oNN = 8192;
    for (int kt = 0; kt < nk; ++kt) {
        // wait: tile kt fully landed (in-order vmcnt retirement, m135);
        // tile kt+1's loads remain in flight across the barrier (T4).
        if (kt + 1 < nk) {
            if (DUAL) asm volatile("s_waitcnt vmcnt(6)" ::: "memory");
            else      asm volatile("s_waitcnt vmcnt(4)" ::: "memory");
        } else {
            asm volatile("s_waitcnt vmcnt(0)" ::: "memory");
        }
        __builtin_amdgcn_s_barrier();
        __builtin_amdgcn_sched_barrier(0);   // pin LDS reads below the barrier
        if (kt + 2 < nk) STAGE(oNN);         // overwrites buffer consumed at kt-1

        const char* Abase = (const char*)(As + oC);
        const char* Bbase = (const char*)(Bs + oC);
        const char* Cbase = (const char*)(B2s + oC);
        short8 af[4], bfr[4], cfr[4];
        #pragma unroll
        for (int i = 0; i < 4; ++i) {
            af[i]  = *(const short8*)(Abase + (wm * 64 + i * 16 + lm) * 64 + xoff);
            bfr[i] = *(const short8*)(Bbase + (wn * 64 + i * 16 + lm) * 64 + xoff);
            if (DUAL) cfr[i] = *(const short8*)(Cbase + (wn * 64 + i * 16 + lm) * 64 + xoff);
        }
        #pragma unroll
        for (int i = 0; i < 4; ++i)
            #pragma unroll
            for (int j = 0; j < 4; ++j) {
                acc[i][j] = __builtin_amdgcn_mfma_f32_16x16x32_bf16(af[i], bfr[j], acc[i][j], 0, 0, 0);
                if (DUAL)
                    acc2[i][j] = __builtin_amdgcn_mfma_f32_16x16x32_bf16(af[i], cfr[j], acc2[i][j], 0, 0, 0);
            }
        const int tmp = oC; oC = oN; oN = oNN; oNN = tmp;   // rotate buffers
    }
#undef STAGE

    const int lg = l >> 4;
    float* Cf = (float*)Cv;
    u16*   Cb = (u16*)Cv;
    #pragma unroll
    for (int i = 0; i < 4; ++i) {
        const size_t row0 = (size_t)bm * 128 + wm * 64 + i * 16 + lg * 4;
        #pragma unroll
        for (int j = 0; j < 4; ++j) {
            const size_t col = (size_t)bn * 128 + wn * 64 + j * 16 + lm;
            #pragma unroll
            for (int r = 0; r < 4; ++r) {
                const size_t idx = (row0 + r) * (size_t)N + col;
                float v = acc[i][j][r];
                if (EPI == 3) v = gelu_tanh(v) * acc2[i][j][r];
                if (RES)      v += R[idx];
                if (OBF) Cb[idx] = f2bf(v);
                else     Cf[idx] = v;
            }
        }
    }
}

// ---------------- MFMA sliding-window attention w/ fused RoPE ----------------
__device__ __forceinline__ u16* ldsAddr(u16* base, int row, int col) {
    const int ch = (col >> 3) ^ (row & 7);
    return base + row * 64 + ch * 8 + (col & 7);
}

__global__ __launch_bounds__(256)
void attn_kernel(const u16* __restrict__ qkv, const int* __restrict__ pmask,
                 const float* __restrict__ cosT, const float* __restrict__ sinT,
                 u16* __restrict__ out) {
    const int qt = blockIdx.x, h = blockIdx.y, b = blockIdx.z;
    const int q0 = qt * 64;
    const int t = threadIdx.x;
    const int w = t >> 6, l = t & 63;
    const int lm = l & 15, lg = l >> 4;

    __shared__ u16 Qs[64 * 64];
    __shared__ u16 Ks[64 * 64];
    __shared__ u16 Vt[64 * 64];   // transposed: rows = d, cols = key
    __shared__ u16 Ps[64 * 64];

    // ---- stage Q with rope ----
    {
        const int r = t >> 2, j0 = (t & 3) * 8;
        const int s = q0 + r;
        const u16* qrow = qkv + (size_t)(b * SEQ + s) * (3 * DM) + h * DH;
        ushort8 lo = *(const ushort8*)(qrow + j0);
        ushort8 hi = *(const ushort8*)(qrow + j0 + 32);
        const float* cr = cosT + (size_t)s * 32 + j0;
        const float* sr = sinT + (size_t)s * 32 + j0;
        ushort8 olo, ohi;
        #pragma unroll
        for (int e = 0; e < 8; ++e) {
            float c = cr[e], sn = sr[e];
            float xl = bf2f(lo[e]), xh = bf2f(hi[e]);
            olo[e] = f2bf(xl * c - xh * sn);
            ohi[e] = f2bf(xh * c + xl * sn);
        }
        *(ushort8*)ldsAddr(Qs, r, j0)      = olo;
        *(ushort8*)ldsAddr(Qs, r, j0 + 32) = ohi;
    }

    f32x4 oacc[4] = {};
    float Mrun[4], Lrun[4];
    #pragma unroll
    for (int r = 0; r < 4; ++r) { Mrun[r] = -3.0e38f; Lrun[r] = 0.f; }

    for (int kb = 0; kb < 3; ++kb) {
        const int kstart = q0 - 64 + kb * 64;
        __syncthreads();
        // ---- stage K with rope ----
        {
            const int r = t >> 2, j0 = (t & 3) * 8;
            const int kg = kstart + r;
            ushort8 olo = {}, ohi = {};
            if (kg >= 0 && kg < SEQ) {
                const u16* krow = qkv + (size_t)(b * SEQ + kg) * (3 * DM) + DM + h * DH;
                ushort8 lo = *(const ushort8*)(krow + j0);
                ushort8 hi = *(const ushort8*)(krow + j0 + 32);
                const float* cr = cosT + (size_t)kg * 32 + j0;
                const float* sr = sinT + (size_t)kg * 32 + j0;
                #pragma unroll
                for (int e = 0; e < 8; ++e) {
                    float c = cr[e], sn = sr[e];
                    float xl = bf2f(lo[e]), xh = bf2f(hi[e]);
                    olo[e] = f2bf(xl * c - xh * sn);
                    ohi[e] = f2bf(xh * c + xl * sn);
                }
            }
            *(ushort8*)ldsAddr(Ks, r, j0)      = olo;
            *(ushort8*)ldsAddr(Ks, r, j0 + 32) = ohi;
        }
        // ---- stage V transposed ----
        {
            const int key = l;
            const int kg = kstart + key;
            const int d0 = w * 16;
            if (kg >= 0 && kg < SEQ) {
                const u16* vrow = qkv + (size_t)(b * SEQ + kg) * (3 * DM) + 2 * DM + h * DH + d0;
                ushort8 v0 = *(const ushort8*)(vrow);
                ushort8 v1 = *(const ushort8*)(vrow + 8);
                #pragma unroll
                for (int e = 0; e < 8; ++e) {
                    *ldsAddr(Vt, d0 + e, key)     = v0[e];
                    *ldsAddr(Vt, d0 + 8 + e, key) = v1[e];
                }
            } else {
                #pragma unroll
                for (int e = 0; e < 16; ++e) *ldsAddr(Vt, d0 + e, key) = 0;
            }
        }
        __syncthreads();

        // ---- QK^T ----
        short8 af[2];
        #pragma unroll
        for (int ks = 0; ks < 2; ++ks)
            af[ks] = *(const short8*)ldsAddr(Qs, w * 16 + lm, ks * 32 + lg * 8);
        f32x4 sacc[4];
        #pragma unroll
        for (int j = 0; j < 4; ++j) {
            f32x4 z = {};
            #pragma unroll
            for (int ks = 0; ks < 2; ++ks) {
                short8 kf = *(const short8*)ldsAddr(Ks, j * 16 + lm, ks * 32 + lg * 8);
                z = __builtin_amdgcn_mfma_f32_16x16x32_bf16(af[ks], kf, z, 0, 0, 0);
            }
            sacc[j] = z;
        }

        // ---- scale + mask ----
        float p[4][4];
        int pmj[4], kgj[4];
        #pragma unroll
        for (int j = 0; j < 4; ++j) {
            kgj[j] = kstart + j * 16 + lm;
            pmj[j] = (kgj[j] >= 0 && kgj[j] < SEQ) ? pmask[b * SEQ + kgj[j]] : 0;
        }
        float mt[4] = {-3.0e38f, -3.0e38f, -3.0e38f, -3.0e38f};
        #pragma unroll
        for (int j = 0; j < 4; ++j)
            #pragma unroll
            for (int r = 0; r < 4; ++r) {
                const int qg = q0 + w * 16 + lg * 4 + r;
                const int diff = qg - kgj[j];
                float v = sacc[j][r] * 0.125f;
                const bool valid = (pmj[j] != 0) && (diff <= HALFW) && (diff >= -HALFW);
                v = valid ? v : -3.0e38f;
                p[j][r] = v;
                mt[r] = fmaxf(mt[r], v);
            }

        // ---- online softmax ----
        #pragma unroll
        for (int r = 0; r < 4; ++r) {
            float m = mt[r];
            m = fmaxf(m, __shfl_xor(m, 1));
            m = fmaxf(m, __shfl_xor(m, 2));
            m = fmaxf(m, __shfl_xor(m, 4));
            m = fmaxf(m, __shfl_xor(m, 8));
            const float Mnew = fmaxf(Mrun[r], m);
            float ps = 0.f;
            #pragma unroll
            for (int j = 0; j < 4; ++j) {
                float e = (p[j][r] > -1.0e37f) ? expf(p[j][r] - Mnew) : 0.0f;
                p[j][r] = e; ps += e;
            }
            ps += __shfl_xor(ps, 1); ps += __shfl_xor(ps, 2);
            ps += __shfl_xor(ps, 4); ps += __shfl_xor(ps, 8);
            const float scale = expf(Mrun[r] - Mnew);
            Lrun[r] = Lrun[r] * scale + ps;
            Mrun[r] = Mnew;
            #pragma unroll
            for (int jd = 0; jd < 4; ++jd) oacc[jd][r] *= scale;
        }

        // ---- P -> LDS (wave-local rows) ----
        #pragma unroll
        for (int j = 0; j < 4; ++j)
            #pragma unroll
            for (int r = 0; r < 4; ++r)
                *ldsAddr(Ps, w * 16 + lg * 4 + r, j * 16 + lm) = f2bf(p[j][r]);

        // ---- PV ----
        #pragma unroll
        for (int ks = 0; ks < 2; ++ks) {
            short8 pa = *(const short8*)ldsAddr(Ps, w * 16 + lm, ks * 32 + lg * 8);
            #pragma unroll
            for (int jd = 0; jd < 4; ++jd) {
                short8 vb = *(const short8*)ldsAddr(Vt, jd * 16 + lm, ks * 32 + lg * 8);
                oacc[jd] = __builtin_amdgcn_mfma_f32_16x16x32_bf16(pa, vb, oacc[jd], 0, 0, 0);
            }
        }
    }

    // ---- normalize + store bf16 ----
    #pragma unroll
    for (int r = 0; r < 4; ++r) {
        const float inv = (Lrun[r] > 0.f) ? 1.0f / Lrun[r] : 0.0f;
        const size_t row = (size_t)(b * SEQ + q0 + w * 16 + lg * 4 + r);
        #pragma unroll
        for (int jd = 0; jd < 4; ++jd)
            out[row * DM + h * DH + jd * 16 + lm] = f2bf(oacc[jd][r] * inv);
    }
}

// ---------------- driver ----------------
extern "C" void kernel_launch(void* const* d_in, const int* in_sizes, int n_in,
                              void* d_out, int out_size, void* d_ws, size_t ws_size,
                              hipStream_t stream) {
    const float* x      = (const float*)d_in[0];
    const int*   pmask  = (const int*)  d_in[1];
    const float* w_qkv  = (const float*)d_in[2];
    const float* w_o    = (const float*)d_in[3];
    const float* g_attn = (const float*)d_in[4];
    const float* g_mlp  = (const float*)d_in[5];
    const float* w_i0   = (const float*)d_in[6];
    const float* w_i1   = (const float*)d_in[7];
    const float* w_mo   = (const float*)d_in[8];
    float* out = (float*)d_out;

    char* ws = (char*)d_ws;
    u16* Wqkv = (u16*)ws;                ws += (size_t)768 * 2304 * 2;
    u16* Wo   = (u16*)ws;                ws += (size_t)768 * 768 * 2;
    u16* Wi0  = (u16*)ws;                ws += (size_t)768 * 1152 * 2;
    u16* Wi1  = (u16*)ws;                ws += (size_t)768 * 1152 * 2;
    u16* Wmo  = (u16*)ws;                ws += (size_t)1152 * 768 * 2;
    u16* hB    = (u16*)ws;               ws += (size_t)NTOK * DM * 2;
    u16* qkvB  = (u16*)ws;               ws += (size_t)NTOK * 3 * DM * 2;
    u16* attnB = (u16*)ws;               ws += (size_t)NTOK * DM * 2;
    u16* prodB = (u16*)ws;               ws += (size_t)NTOK * DI * 2;
    float* ropeCos = (float*)ws;         ws += (size_t)SEQ * 32 * 4;
    float* ropeSin = (float*)ws;         ws += (size_t)SEQ * 32 * 4;

    // 0. tables + weight transpose/convert
    rope_table_kernel<<<SEQ * 32 / 256, 256, 0, stream>>>(ropeCos, ropeSin);
    wtrans_kernel<<<dim3(2304 / 32, 768 / 32), 256, 0, stream>>>(w_qkv, Wqkv, 768, 2304);
    wtrans_kernel<<<dim3(768 / 32, 768 / 32),  256, 0, stream>>>(w_o,   Wo,   768, 768);
    wtrans_kernel<<<dim3(1152 / 32, 768 / 32), 256, 0, stream>>>(w_i0,  Wi0,  768, 1152);
    wtrans_kernel<<<dim3(1152 / 32, 768 / 32), 256, 0, stream>>>(w_i1,  Wi1,  768, 1152);
    wtrans_kernel<<<dim3(768 / 32, 1152 / 32), 256, 0, stream>>>(w_mo,  Wmo,  1152, 768);

    // 1. h = rmsnorm(x) -> bf16
    rmsnorm_kernel<<<NTOK, 256, 0, stream>>>(x, g_attn, hB);
    // 2. qkv = h @ w_qkv -> bf16   (1D grid, nbn = 18)
    bgemm_kernel<0, false, true, false><<<(NTOK / 128) * (2304 / 128), 256, 0, stream>>>(
        hB, Wqkv, nullptr, qkvB, nullptr, NTOK, 2304, 768, 2304 / 128);
    // 3+4. attention (rope fused) -> bf16
    attn_kernel<<<dim3(SEQ / 64, NHEAD, BATCH), 256, 0, stream>>>(
        qkvB, pmask, ropeCos, ropeSin, attnB);
    // 5. x1 = x + attn @ w_o -> fp32 d_out   (nbn = 6)
    bgemm_kernel<0, true, false, false><<<(NTOK / 128) * (768 / 128), 256, 0, stream>>>(
        attnB, Wo, nullptr, out, x, NTOK, 768, 768, 768 / 128);
    // 6. h2 = rmsnorm(x1) -> bf16
    rmsnorm_kernel<<<NTOK, 256, 0, stream>>>(out, g_mlp, hB);
    // 7+8. prod = gelu(h2 @ w_i0) * (h2 @ w_i1) -> bf16   (nbn = 9)
    bgemm_kernel<3, false, true, true><<<(NTOK / 128) * (1152 / 128), 256, 0, stream>>>(
        hB, Wi0, Wi1, prodB, nullptr, NTOK, 1152, 768, 1152 / 128);
    // 9. out = x1 + prod @ w_mo (in-place residual)   (nbn = 6)
    bgemm_kernel<0, true, false, false><<<(NTOK / 128) * (768 / 128), 256, 0, stream>>>(
        prodB, Wmo, nullptr, out, out, NTOK, 768, 1152, 768 / 128);
}

// Round 6
// 298.105 us; speedup vs baseline: 1.1620x; 1.1620x over previous
//
#include <hip/hip_runtime.h>
#include <hip/hip_bf16.h>
#include <math.h>

// ---------------- constants ----------------
#define SEQ   4096
#define BATCH 2
#define DM    768
#define DI    1152
#define NHEAD 12
#define DH    64
#define NTOK  (BATCH * SEQ)   // 8192
#define HALFW 64              // WINDOW//2

typedef unsigned short u16;
typedef __attribute__((ext_vector_type(8))) short   short8;   // 8 bf16 = MFMA A/B frag
typedef __attribute__((ext_vector_type(4))) float   f32x4;    // MFMA C/D frag
typedef __attribute__((ext_vector_type(8))) unsigned short ushort8;

__device__ __forceinline__ u16 f2bf(float f) {
    unsigned int u = __float_as_uint(f);
    u += 0x7fffu + ((u >> 16) & 1u);   // RNE
    return (u16)(u >> 16);
}
__device__ __forceinline__ float bf2f(u16 b) {
    return __uint_as_float(((unsigned int)b) << 16);
}

__device__ __forceinline__ void gload16(const void* g, void* l) {
    __builtin_amdgcn_global_load_lds(
        (const __attribute__((address_space(1))) void*)g,
        (__attribute__((address_space(3))) void*)l, 16, 0, 0);
}

__device__ __forceinline__ float gelu_tanh(float v) {
    return 0.5f * v * (1.0f + tanhf(0.7978845608028654f * (v + 0.044715f * v * v * v)));
}

// ---------------- weight transpose + bf16 convert ----------------
// W: fp32 [K][N] -> WT: bf16 [N][K].  ILV: output row n' = (n/64)*128 + ofs + n%64
// (interleaves two weight matrices at 64-col granularity for the fused MLP GEMM).
template<bool ILV>
__global__ __launch_bounds__(256)
void wtrans_kernel(const float* __restrict__ W, u16* __restrict__ WT,
                   int K, int N, int ofs) {
    __shared__ float S[32][33];
    const int tn = blockIdx.x, tk = blockIdx.y;
    const int tx = threadIdx.x & 31, ty = threadIdx.x >> 5;
    #pragma unroll
    for (int i = 0; i < 4; ++i) {
        const int r = ty + i * 8;
        S[r][tx] = W[(size_t)(tk * 32 + r) * N + tn * 32 + tx];
    }
    __syncthreads();
    #pragma unroll
    for (int i = 0; i < 4; ++i) {
        const int r = ty + i * 8;
        const int n = tn * 32 + r;
        const int np = ILV ? ((n >> 6) * 128 + ofs + (n & 63)) : n;
        WT[(size_t)np * K + tk * 32 + tx] = f2bf(S[tx][r]);
    }
}

// ---------------- rope cos/sin table: [s][j], j=0..31 ----------------
__global__ __launch_bounds__(256)
void rope_table_kernel(float* __restrict__ cosT, float* __restrict__ sinT) {
    const int id = blockIdx.x * 256 + threadIdx.x;   // SEQ*32
    const int j = id & 31, s = id >> 5;
    const float inv = powf(10000.0f, -(float)j * (1.0f / 32.0f));
    const float ph = (float)s * inv;
    cosT[id] = cosf(ph);
    sinT[id] = sinf(ph);
}

// ---------------- RMSNorm (fp32 in -> bf16 out) ----------------
__global__ __launch_bounds__(256)
void rmsnorm_kernel(const float* __restrict__ x, const float* __restrict__ g,
                    u16* __restrict__ out) {
    const int row = blockIdx.x;
    const int t = threadIdx.x;
    const float* xr = x + (size_t)row * DM;
    float a = xr[t], b = xr[t + 256], c = xr[t + 512];
    float ss = a * a + b * b + c * c;
    #pragma unroll
    for (int o = 32; o > 0; o >>= 1) ss += __shfl_xor(ss, o);
    __shared__ float red[4];
    if ((t & 63) == 0) red[t >> 6] = ss;
    __syncthreads();
    float tot = red[0] + red[1] + red[2] + red[3];
    float inv = 1.0f / sqrtf(tot * (1.0f / DM) + 1e-5f);
    u16* orow = out + (size_t)row * DM;
    orow[t]       = f2bf(a * inv * g[t]);
    orow[t + 256] = f2bf(b * inv * g[t + 256]);
    orow[t + 512] = f2bf(c * inv * g[t + 512]);
}

// ---------------- bf16 MFMA GEMM (round-4 double-buffer, XCD-swizzled) ----------
// A bf16 [M][K]; B bf16 [NB][K] pre-transposed (NB = nbn*128 rows).
// EPI: 0 none, 3 swiglu-exchange (B rows interleaved gate|up per 128; output
//      width N = nbn*64, block writes 64 cols = gelu(gate)*up via LDS exchange).
// RES: += R(fp32).  OBF: bf16 out else fp32.  1D grid, nbn = B-rows/128.
template<int EPI, bool RES, bool OBF>
__global__ __launch_bounds__(256)
void bgemm_kernel(const u16* __restrict__ A, const u16* __restrict__ B,
                  void* __restrict__ Cv, const float* __restrict__ R,
                  int M, int N, int K, int nbn) {
    __shared__ u16 SM[16384];          // 32 KB: As @0/@4096, Bs @8192/@12288
    u16* As = SM;
    u16* Bs = SM + 8192;
    const int t = threadIdx.x;
    const int w = t >> 6, l = t & 63;
    const int wm = w >> 1, wn = w & 1;

    // bijective XCD swizzle (m204): bn fastest within each XCD's contiguous chunk.
    const int nb = gridDim.x;
    const int orig = blockIdx.x;
    const int qq = nb >> 3, rr = nb & 7;
    const int xcd = orig & 7, cidx = orig >> 3;
    const int wgid = (xcd < rr ? xcd * (qq + 1) : rr * (qq + 1) + (xcd - rr) * qq) + cidx;
    const int bm = wgid / nbn, bn = wgid % nbn;

    // staging: slot s holds row m=s>>2, k-chunk ((s&3) ^ ((s>>3)&3))
    const int s0 = (w * 2 + 0) * 64 + l;
    const int s1 = (w * 2 + 1) * 64 + l;
    const int am0 = s0 >> 2, ak0 = ((s0 & 3) ^ ((s0 >> 3) & 3)) * 8;
    const int am1 = s1 >> 2, ak1 = ((s1 & 3) ^ ((s1 >> 3) & 3)) * 8;
    const u16* aSrc0 = A + (size_t)(bm * 128 + am0) * K + ak0;
    const u16* aSrc1 = A + (size_t)(bm * 128 + am1) * K + ak1;
    const u16* bSrc0 = B + (size_t)(bn * 128 + am0) * K + ak0;
    const u16* bSrc1 = B + (size_t)(bn * 128 + am1) * K + ak1;
    const int dS0 = (w * 2 + 0) * 512;
    const int dS1 = (w * 2 + 1) * 512;

    const int lm = l & 15, lk = l >> 4;
    const int xoff = ((lk ^ ((lm >> 1) & 3)) * 16);   // byte offset within 64B row

    f32x4 acc[4][4] = {};

    const int nk = K >> 5;

#define STAGE(pp)  do {                                                        \
        u16* a_ = As + (pp) * 4096;  u16* b_ = Bs + (pp) * 4096;               \
        gload16(aSrc0, a_ + dS0);  gload16(aSrc1, a_ + dS1);                   \
        gload16(bSrc0, b_ + dS0);  gload16(bSrc1, b_ + dS1);                   \
        aSrc0 += 32; aSrc1 += 32; bSrc0 += 32; bSrc1 += 32;                    \
    } while (0)

    STAGE(0);
    __syncthreads();   // drains vmcnt: buf0 ready
    int p = 0;
    for (int kt = 0; kt < nk; ++kt) {
        if (kt + 1 < nk) STAGE(p ^ 1);   // lands by end-of-iter barrier

        const char* Abase = (const char*)(As + p * 4096);
        const char* Bbase = (const char*)(Bs + p * 4096);
        short8 af[4], bfr[4];
        #pragma unroll
        for (int i = 0; i < 4; ++i) {
            af[i]  = *(const short8*)(Abase + (wm * 64 + i * 16 + lm) * 64 + xoff);
            bfr[i] = *(const short8*)(Bbase + (wn * 64 + i * 16 + lm) * 64 + xoff);
        }
        #pragma unroll
        for (int i = 0; i < 4; ++i)
            #pragma unroll
            for (int j = 0; j < 4; ++j)
                acc[i][j] = __builtin_amdgcn_mfma_f32_16x16x32_bf16(af[i], bfr[j], acc[i][j], 0, 0, 0);
        __syncthreads();   // next buf ready, this buf's reads done
        p ^= 1;
    }
#undef STAGE

    const int lg = l >> 4;
    float* Cf = (float*)Cv;
    u16*   Cb = (u16*)Cv;

    if (EPI == 3) {
        // swiglu exchange: tile cols 0-63 (wn=0 waves) = gate, 64-127 (wn=1) = up.
        float* ex = (float*)SM;   // reuse staging LDS: 128 rows x 64 cols fp32 = 32 KB
        if (wn == 1) {
            #pragma unroll
            for (int i = 0; i < 4; ++i)
                #pragma unroll
                for (int j = 0; j < 4; ++j)
                    #pragma unroll
                    for (int r = 0; r < 4; ++r)
                        ex[(wm * 64 + i * 16 + lg * 4 + r) * 64 + j * 16 + lm] = acc[i][j][r];
        }
        __syncthreads();
        if (wn == 0) {
            #pragma unroll
            for (int i = 0; i < 4; ++i) {
                const int lrow0 = wm * 64 + i * 16 + lg * 4;
                const size_t grow0 = (size_t)bm * 128 + lrow0;
                #pragma unroll
                for (int j = 0; j < 4; ++j) {
                    const int c = j * 16 + lm;
                    #pragma unroll
                    for (int r = 0; r < 4; ++r) {
                        const float up = ex[(lrow0 + r) * 64 + c];
                        const float v = gelu_tanh(acc[i][j][r]) * up;
                        Cb[(grow0 + r) * (size_t)N + (size_t)bn * 64 + c] = f2bf(v);
                    }
                }
            }
        }
        return;
    }

    #pragma unroll
    for (int i = 0; i < 4; ++i) {
        const size_t row0 = (size_t)bm * 128 + wm * 64 + i * 16 + lg * 4;
        #pragma unroll
        for (int j = 0; j < 4; ++j) {
            const size_t col = (size_t)bn * 128 + wn * 64 + j * 16 + lm;
            #pragma unroll
            for (int r = 0; r < 4; ++r) {
                const size_t idx = (row0 + r) * (size_t)N + col;
                float v = acc[i][j][r];
                if (RES) v += R[idx];
                if (OBF) Cb[idx] = f2bf(v);
                else     Cf[idx] = v;
            }
        }
    }
}

// ---------------- MFMA sliding-window attention w/ fused RoPE ----------------
__device__ __forceinline__ u16* ldsAddr(u16* base, int row, int col) {
    const int ch = (col >> 3) ^ (row & 7);
    return base + row * 64 + ch * 8 + (col & 7);
}

__global__ __launch_bounds__(256)
void attn_kernel(const u16* __restrict__ qkv, const int* __restrict__ pmask,
                 const float* __restrict__ cosT, const float* __restrict__ sinT,
                 u16* __restrict__ out) {
    const int qt = blockIdx.x, h = blockIdx.y, b = blockIdx.z;
    const int q0 = qt * 64;
    const int t = threadIdx.x;
    const int w = t >> 6, l = t & 63;
    const int lm = l & 15, lg = l >> 4;

    __shared__ u16 Qs[64 * 64];
    __shared__ u16 Ks[64 * 64];
    __shared__ u16 Vt[64 * 64];   // transposed: rows = d, cols = key
    __shared__ u16 Ps[64 * 64];

    // ---- stage Q with rope ----
    {
        const int r = t >> 2, j0 = (t & 3) * 8;
        const int s = q0 + r;
        const u16* qrow = qkv + (size_t)(b * SEQ + s) * (3 * DM) + h * DH;
        ushort8 lo = *(const ushort8*)(qrow + j0);
        ushort8 hi = *(const ushort8*)(qrow + j0 + 32);
        const float* cr = cosT + (size_t)s * 32 + j0;
        const float* sr = sinT + (size_t)s * 32 + j0;
        ushort8 olo, ohi;
        #pragma unroll
        for (int e = 0; e < 8; ++e) {
            float c = cr[e], sn = sr[e];
            float xl = bf2f(lo[e]), xh = bf2f(hi[e]);
            olo[e] = f2bf(xl * c - xh * sn);
            ohi[e] = f2bf(xh * c + xl * sn);
        }
        *(ushort8*)ldsAddr(Qs, r, j0)      = olo;
        *(ushort8*)ldsAddr(Qs, r, j0 + 32) = ohi;
    }

    f32x4 oacc[4] = {};
    float Mrun[4], Lrun[4];
    #pragma unroll
    for (int r = 0; r < 4; ++r) { Mrun[r] = -3.0e38f; Lrun[r] = 0.f; }

    for (int kb = 0; kb < 3; ++kb) {
        const int kstart = q0 - 64 + kb * 64;
        __syncthreads();
        // ---- stage K with rope ----
        {
            const int r = t >> 2, j0 = (t & 3) * 8;
            const int kg = kstart + r;
            ushort8 olo = {}, ohi = {};
            if (kg >= 0 && kg < SEQ) {
                const u16* krow = qkv + (size_t)(b * SEQ + kg) * (3 * DM) + DM + h * DH;
                ushort8 lo = *(const ushort8*)(krow + j0);
                ushort8 hi = *(const ushort8*)(krow + j0 + 32);
                const float* cr = cosT + (size_t)kg * 32 + j0;
                const float* sr = sinT + (size_t)kg * 32 + j0;
                #pragma unroll
                for (int e = 0; e < 8; ++e) {
                    float c = cr[e], sn = sr[e];
                    float xl = bf2f(lo[e]), xh = bf2f(hi[e]);
                    olo[e] = f2bf(xl * c - xh * sn);
                    ohi[e] = f2bf(xh * c + xl * sn);
                }
            }
            *(ushort8*)ldsAddr(Ks, r, j0)      = olo;
            *(ushort8*)ldsAddr(Ks, r, j0 + 32) = ohi;
        }
        // ---- stage V transposed ----
        {
            const int key = l;
            const int kg = kstart + key;
            const int d0 = w * 16;
            if (kg >= 0 && kg < SEQ) {
                const u16* vrow = qkv + (size_t)(b * SEQ + kg) * (3 * DM) + 2 * DM + h * DH + d0;
                ushort8 v0 = *(const ushort8*)(vrow);
                ushort8 v1 = *(const ushort8*)(vrow + 8);
                #pragma unroll
                for (int e = 0; e < 8; ++e) {
                    *ldsAddr(Vt, d0 + e, key)     = v0[e];
                    *ldsAddr(Vt, d0 + 8 + e, key) = v1[e];
                }
            } else {
                #pragma unroll
                for (int e = 0; e < 16; ++e) *ldsAddr(Vt, d0 + e, key) = 0;
            }
        }
        __syncthreads();

        // ---- QK^T ----
        short8 af[2];
        #pragma unroll
        for (int ks = 0; ks < 2; ++ks)
            af[ks] = *(const short8*)ldsAddr(Qs, w * 16 + lm, ks * 32 + lg * 8);
        f32x4 sacc[4];
        #pragma unroll
        for (int j = 0; j < 4; ++j) {
            f32x4 z = {};
            #pragma unroll
            for (int ks = 0; ks < 2; ++ks) {
                short8 kf = *(const short8*)ldsAddr(Ks, j * 16 + lm, ks * 32 + lg * 8);
                z = __builtin_amdgcn_mfma_f32_16x16x32_bf16(af[ks], kf, z, 0, 0, 0);
            }
            sacc[j] = z;
        }

        // ---- scale + mask ----
        float p[4][4];
        int pmj[4], kgj[4];
        #pragma unroll
        for (int j = 0; j < 4; ++j) {
            kgj[j] = kstart + j * 16 + lm;
            pmj[j] = (kgj[j] >= 0 && kgj[j] < SEQ) ? pmask[b * SEQ + kgj[j]] : 0;
        }
        float mt[4] = {-3.0e38f, -3.0e38f, -3.0e38f, -3.0e38f};
        #pragma unroll
        for (int j = 0; j < 4; ++j)
            #pragma unroll
            for (int r = 0; r < 4; ++r) {
                const int qg = q0 + w * 16 + lg * 4 + r;
                const int diff = qg - kgj[j];
                float v = sacc[j][r] * 0.125f;
                const bool valid = (pmj[j] != 0) && (diff <= HALFW) && (diff >= -HALFW);
                v = valid ? v : -3.0e38f;
                p[j][r] = v;
                mt[r] = fmaxf(mt[r], v);
            }

        // ---- online softmax ----
        #pragma unroll
        for (int r = 0; r < 4; ++r) {
            float m = mt[r];
            m = fmaxf(m, __shfl_xor(m, 1));
            m = fmaxf(m, __shfl_xor(m, 2));
            m = fmaxf(m, __shfl_xor(m, 4));
            m = fmaxf(m, __shfl_xor(m, 8));
            const float Mnew = fmaxf(Mrun[r], m);
            float ps = 0.f;
            #pragma unroll
            for (int j = 0; j < 4; ++j) {
                float e = (p[j][r] > -1.0e37f) ? expf(p[j][r] - Mnew) : 0.0f;
                p[j][r] = e; ps += e;
            }
            ps += __shfl_xor(ps, 1); ps += __shfl_xor(ps, 2);
            ps += __shfl_xor(ps, 4); ps += __shfl_xor(ps, 8);
            const float scale = expf(Mrun[r] - Mnew);
            Lrun[r] = Lrun[r] * scale + ps;
            Mrun[r] = Mnew;
            #pragma unroll
            for (int jd = 0; jd < 4; ++jd) oacc[jd][r] *= scale;
        }

        // ---- P -> LDS (wave-local rows) ----
        #pragma unroll
        for (int j = 0; j < 4; ++j)
            #pragma unroll
            for (int r = 0; r < 4; ++r)
                *ldsAddr(Ps, w * 16 + lg * 4 + r, j * 16 + lm) = f2bf(p[j][r]);

        // ---- PV ----
        #pragma unroll
        for (int ks = 0; ks < 2; ++ks) {
            short8 pa = *(const short8*)ldsAddr(Ps, w * 16 + lm, ks * 32 + lg * 8);
            #pragma unroll
            for (int jd = 0; jd < 4; ++jd) {
                short8 vb = *(const short8*)ldsAddr(Vt, jd * 16 + lm, ks * 32 + lg * 8);
                oacc[jd] = __builtin_amdgcn_mfma_f32_16x16x32_bf16(pa, vb, oacc[jd], 0, 0, 0);
            }
        }
    }

    // ---- normalize + store bf16 ----
    #pragma unroll
    for (int r = 0; r < 4; ++r) {
        const float inv = (Lrun[r] > 0.f) ? 1.0f / Lrun[r] : 0.0f;
        const size_t row = (size_t)(b * SEQ + q0 + w * 16 + lg * 4 + r);
        #pragma unroll
        for (int jd = 0; jd < 4; ++jd)
            out[row * DM + h * DH + jd * 16 + lm] = f2bf(oacc[jd][r] * inv);
    }
}

// ---------------- driver ----------------
extern "C" void kernel_launch(void* const* d_in, const int* in_sizes, int n_in,
                              void* d_out, int out_size, void* d_ws, size_t ws_size,
                              hipStream_t stream) {
    const float* x      = (const float*)d_in[0];
    const int*   pmask  = (const int*)  d_in[1];
    const float* w_qkv  = (const float*)d_in[2];
    const float* w_o    = (const float*)d_in[3];
    const float* g_attn = (const float*)d_in[4];
    const float* g_mlp  = (const float*)d_in[5];
    const float* w_i0   = (const float*)d_in[6];
    const float* w_i1   = (const float*)d_in[7];
    const float* w_mo   = (const float*)d_in[8];
    float* out = (float*)d_out;

    char* ws = (char*)d_ws;
    u16* Wqkv = (u16*)ws;                ws += (size_t)768 * 2304 * 2;
    u16* Wo   = (u16*)ws;                ws += (size_t)768 * 768 * 2;
    u16* Wmlp = (u16*)ws;                ws += (size_t)2304 * 768 * 2;   // interleaved i0|i1
    u16* Wmo  = (u16*)ws;                ws += (size_t)1152 * 768 * 2;
    u16* hB    = (u16*)ws;               ws += (size_t)NTOK * DM * 2;
    u16* qkvB  = (u16*)ws;               ws += (size_t)NTOK * 3 * DM * 2;
    u16* attnB = (u16*)ws;               ws += (size_t)NTOK * DM * 2;
    u16* prodB = (u16*)ws;               ws += (size_t)NTOK * DI * 2;
    float* ropeCos = (float*)ws;         ws += (size_t)SEQ * 32 * 4;
    float* ropeSin = (float*)ws;         ws += (size_t)SEQ * 32 * 4;

    // 0. tables + weight transpose/convert
    rope_table_kernel<<<SEQ * 32 / 256, 256, 0, stream>>>(ropeCos, ropeSin);
    wtrans_kernel<false><<<dim3(2304 / 32, 768 / 32), 256, 0, stream>>>(w_qkv, Wqkv, 768, 2304, 0);
    wtrans_kernel<false><<<dim3(768 / 32, 768 / 32),  256, 0, stream>>>(w_o,   Wo,   768, 768, 0);
    wtrans_kernel<true><<<dim3(1152 / 32, 768 / 32),  256, 0, stream>>>(w_i0,  Wmlp, 768, 1152, 0);
    wtrans_kernel<true><<<dim3(1152 / 32, 768 / 32),  256, 0, stream>>>(w_i1,  Wmlp, 768, 1152, 64);
    wtrans_kernel<false><<<dim3(768 / 32, 1152 / 32), 256, 0, stream>>>(w_mo,  Wmo,  1152, 768, 0);

    // 1. h = rmsnorm(x) -> bf16
    rmsnorm_kernel<<<NTOK, 256, 0, stream>>>(x, g_attn, hB);
    // 2. qkv = h @ w_qkv -> bf16   (nbn = 18)
    bgemm_kernel<0, false, true><<<(NTOK / 128) * (2304 / 128), 256, 0, stream>>>(
        hB, Wqkv, qkvB, nullptr, NTOK, 2304, 768, 2304 / 128);
    // 3+4. attention (rope fused) -> bf16
    attn_kernel<<<dim3(SEQ / 64, NHEAD, BATCH), 256, 0, stream>>>(
        qkvB, pmask, ropeCos, ropeSin, attnB);
    // 5. x1 = x + attn @ w_o -> fp32 d_out   (nbn = 6)
    bgemm_kernel<0, true, false><<<(NTOK / 128) * (768 / 128), 256, 0, stream>>>(
        attnB, Wo, out, x, NTOK, 768, 768, 768 / 128);
    // 6. h2 = rmsnorm(x1) -> bf16
    rmsnorm_kernel<<<NTOK, 256, 0, stream>>>(out, g_mlp, hB);
    // 7+8. prod = gelu(h2 @ w_i0) * (h2 @ w_i1) -> bf16
    //      single GEMM over interleaved Wmlp (B-rows 2304, nbn=18, out width 1152)
    bgemm_kernel<3, false, true><<<(NTOK / 128) * (2304 / 128), 256, 0, stream>>>(
        hB, Wmlp, prodB, nullptr, NTOK, 1152, 768, 2304 / 128);
    // 9. out = x1 + prod @ w_mo (in-place residual)   (nbn = 6)
    bgemm_kernel<0, true, false><<<(NTOK / 128) * (768 / 128), 256, 0, stream>>>(
        prodB, Wmo, out, out, NTOK, 768, 1152, 768 / 128);
}